// Round 11
// baseline (112.027 us; speedup 1.0000x reference)
//
#include <hip/hip_runtime.h>
#include <hip/hip_bf16.h>
#include <math.h>

// Sparsemax over rows of [N_ROWS, 64] fp32 — ROW-PER-LANE from swizzled LDS.
//
// r10 (granule layout + DPP butterflies) = 102.7us, VALU-co-bound: ~10 VALU
// slots/row/iter, 40% of it cross-lane reductions. Here each wave stages its
// 64 rows (16KB) into LDS and each lane iterates ITS OWN row: zero cross-lane
// ops in the loop, ~5 slots/row/iter, SIMD-perfect.
//
//  - XOR swizzle p = f ^ ((f>>4)&15) (involution on float4 index) kills the
//    256B-row-stride bank conflict; iter reads in logical-q order hit bank
//    group (q%8)^(lane&7) — uniform (baseline-equivalent).
//  - Values re-read from LDS each iteration (short-lived regs); per-iter
//    memory clobber stops LICM from hoisting 64 floats (r2-r7 allocator war).
//  - Output: tau redistributed via __shfl; final pass reads LDS physically
//    linear (conflict-free), stores lanes permuted within 256B groups
//    (coalescing is segment-based, order-free).
//
// Michelot fixed point (z=1 simplex threshold), all decisions in fp32
// (r6: fp16 flipped support boundary -> 1/rho jumps):
//   tau0 = max(x)-1 ; tau += (sum(max(0,x-tau))-1)/c ; stop when c fixed.
//   reference's double -1: tau_out = tau* - 1/rho ; out = max(0, x - tau_out)

typedef float nfloat4 __attribute__((ext_vector_type(4)));

__global__ __launch_bounds__(128) void sparsemax_rowlane(
    const float* __restrict__ x, float* __restrict__ out, long long n_rows) {
    __shared__ __align__(16) float lds[2][4096];   // 16KB per wave
    const int lane = threadIdx.x & 63;
    const int w = threadIdx.x >> 6;
    const long long gw = (long long)blockIdx.x * 2 + w;
    const long long row0 = gw << 6;                // 64 rows per wave
    if (row0 >= n_rows) return;
    float* W = lds[w];

    const nfloat4* __restrict__ xv4 = reinterpret_cast<const nfloat4*>(x);
    nfloat4* __restrict__ ov4 = reinterpret_cast<nfloat4*>(out);
    const long long gbase = row0 << 4;             // float4 idx of wave's tile
    const long long f4_total = n_rows << 4;
    const bool full = (row0 + 64) <= n_rows;

    // ---- stage: global (linear, coalesced) -> LDS (swizzled) ----
#pragma unroll
    for (int i = 0; i < 16; ++i) {
        const int f = i * 64 + lane;               // logical float4 idx in tile
        const int p = f ^ ((f >> 4) & 15);         // physical (swizzled)
        nfloat4 v = {0.0f, 0.0f, 0.0f, 0.0f};
        if (full || (gbase + f) < f4_total) v = xv4[gbase + f];
        *reinterpret_cast<nfloat4*>(&W[p * 4]) = v;
    }
    asm volatile("" ::: "memory");   // order staging before reads

    // ---- per-lane row max (reads in logical-q order: conflict-free) ----
    const int rbase = lane * 16;     // physical float4 base of this lane's row
    const int sw = lane & 15;
    float m = -INFINITY;
#pragma unroll
    for (int q = 0; q < 16; ++q) {
        const nfloat4 v =
            *reinterpret_cast<const nfloat4*>(&W[(rbase + (q ^ sw)) * 4]);
        m = fmaxf(m, fmaxf(fmaxf(v.x, v.y), fmaxf(v.z, v.w)));
    }

    // ---- Michelot iterations, one row per lane, no cross-lane ops ----
    float tau = m - 1.0f;            // lower bound on tau*
    float cprev = -1.0f;             // force at least one iteration
    float rfin = 1.0f;
    for (int it = 0; it < 40; ++it) {
        asm volatile("" ::: "memory");   // re-read LDS; no 64-float residency
        float s0 = 0.0f, s1 = 0.0f;
        float c0 = 0.0f, c1 = 0.0f;
#pragma unroll
        for (int q = 0; q < 16; ++q) {
            const nfloat4 v =
                *reinterpret_cast<const nfloat4*>(&W[(rbase + (q ^ sw)) * 4]);
            const float d0 = v.x - tau, d1 = v.y - tau;
            const float d2 = v.z - tau, d3 = v.w - tau;
            s0 += fmaxf(d0, 0.0f); c0 += (d0 > 0.0f) ? 1.0f : 0.0f;
            s1 += fmaxf(d1, 0.0f); c1 += (d1 > 0.0f) ? 1.0f : 0.0f;
            s0 += fmaxf(d2, 0.0f); c0 += (d2 > 0.0f) ? 1.0f : 0.0f;
            s1 += fmaxf(d3, 0.0f); c1 += (d3 > 0.0f) ? 1.0f : 0.0f;
        }
        const float s = s0 + s1;
        const float c = c0 + c1;
        const bool done = (c == cprev);  // nested supports: same count == fixed
        cprev = c;
        const float r = __builtin_amdgcn_rcpf(c);
        rfin = r;
        tau += (s - 1.0f) * r;           // idempotent once converged
        if (__all(done)) break;
    }
    const float tau_out = tau - rfin;    // reference's double -1: tau* - 1/rho

    // ---- output: physically-linear LDS read (conflict-free) + coalesced
    //      stores (lanes permuted within 256B groups) ----
#pragma unroll
    for (int i = 0; i < 16; ++i) {
        const int p = i * 64 + lane;                 // physical idx, linear
        const int f = p ^ ((p >> 4) & 15);           // logical idx (involution)
        const int row = p >> 4;                      // tile-local row
        const float tr = __shfl(tau_out, row, 64);   // row's tau from its lane
        const nfloat4 v = *reinterpret_cast<const nfloat4*>(&W[p * 4]);
        nfloat4 t;
        t.x = fmaxf(0.0f, v.x - tr);
        t.y = fmaxf(0.0f, v.y - tr);
        t.z = fmaxf(0.0f, v.z - tr);
        t.w = fmaxf(0.0f, v.w - tr);
        if (full || (gbase + f) < f4_total)
            __builtin_nontemporal_store(t, &ov4[gbase + f]);
    }
}

extern "C" void kernel_launch(void* const* d_in, const int* in_sizes, int n_in,
                              void* d_out, int out_size, void* d_ws, size_t ws_size,
                              hipStream_t stream) {
    const float* x = (const float*)d_in[0];
    float* out = (float*)d_out;
    const long long n_rows = in_sizes[0] / 64;

    const int block = 128;                           // 2 waves = 128 rows
    const long long grid = (n_rows + 127) / 128;     // 8192 for 1M rows
    sparsemax_rowlane<<<(int)grid, block, 0, stream>>>(x, out, n_rows);
}

// Round 12
// 84.641 us; speedup vs baseline: 1.3236x; 1.3236x over previous
//
#include <hip/hip_runtime.h>
#include <hip/hip_bf16.h>
#include <math.h>

// Sparsemax over rows of [N_ROWS, 64] fp32 — PAIR-PER-ROW registers, LDS only
// as a transpose buffer.
//
// Ladder so far: r8 2-lanes/row regs = 145us (scattered VMEM: 64 segs/instr);
// r10 granule+DPP = 102.7us (coalesced, but 8.25 VALU slots/row/iter, VALU
// co-bound at ~62us vs ~64us HBM floor); r11 row-per-lane-from-LDS = 112us
// (16 ds_read_b128/iter + 10 waves/CU -> latency-bound).
//
// This kernel: coalesced global I/O (r10's win) + register-resident iteration
// at 32 floats/lane (r8's spill-free budget) + row-parallel Michelot (r11's
// VALU win). LDS (8KB/wave) is touched exactly 4x per value: stage-in write,
// pair-read, result write, coalesced-out read. Swizzle phys = r*16 + (q^(r&7))
// (f4 units) makes all four phases bank-conflict-free (each bank-quad hit by
// exactly 8 of 64 lanes in every slot). Iteration loop: zero DS ops — the
// pair combine __shfl_xor(.,1) lowers to DPP quad_perm (VALU pipe).
//
// Michelot fixed point (z=1 simplex threshold), all decisions fp32
// (r6: fp16 flipped the support boundary -> 1/rho output jumps):
//   tau0 = max(x)-1 ; tau += (sum(max(0,x-tau))-1)/c ; stop when c fixed
//   (supports nested/shrinking; update idempotent at the fixed point).
//   reference's double -1: tau_out = tau* - 1/rho ; out = max(0, x - tau_out)

typedef float nfloat4 __attribute__((ext_vector_type(4)));

#define FOR8(OP) OP(0) OP(1) OP(2) OP(3) OP(4) OP(5) OP(6) OP(7)

__device__ __forceinline__ nfloat4 v4max(nfloat4 a, nfloat4 b) {
    nfloat4 r;
    r.x = fmaxf(a.x, b.x); r.y = fmaxf(a.y, b.y);
    r.z = fmaxf(a.z, b.z); r.w = fmaxf(a.w, b.w);
    return r;
}

__global__ __launch_bounds__(256) void sparsemax_pairlds(
    const float* __restrict__ x, float* __restrict__ out, long long n_rows) {
    __shared__ nfloat4 lds4[4][512];   // 8 KB per wave, 32 KB per block
    const int lane = threadIdx.x & 63;
    const int w = threadIdx.x >> 6;
    const long long gw = (long long)blockIdx.x * 4 + w;
    const long long row0 = gw * 32;               // 32 rows per wave
    nfloat4* W = lds4[w];

    const nfloat4* __restrict__ xv = reinterpret_cast<const nfloat4*>(x);
    nfloat4* __restrict__ ov = reinterpret_cast<nfloat4*>(out);
    const long long gbase = row0 * 16;            // f4 index of tile
    const long long f4max = n_rows * 16;

    const bool active = row0 < n_rows;            // per-wave
    const bool full = (row0 + 32) <= n_rows;
    const int hi4 = lane >> 4;
    const int l15 = lane & 15;

    // ---- stage in: global coalesced -> LDS swizzled (conflict-free) ----
    if (active) {
        if (full) {
#pragma unroll
            for (int i = 0; i < 8; ++i) {
                const int r = i * 4 + hi4;
                W[r * 16 + (l15 ^ (r & 7))] = xv[gbase + i * 64 + lane];
            }
        } else {
#pragma unroll
            for (int i = 0; i < 8; ++i) {
                const int r = i * 4 + hi4;
                nfloat4 t = {0.f, 0.f, 0.f, 0.f};
                if (gbase + i * 64 + lane < f4max) t = xv[gbase + i * 64 + lane];
                W[r * 16 + (l15 ^ (r & 7))] = t;
            }
        }
    }
    __syncthreads();

    const int prow = lane >> 1;                   // tile-local row of this pair
    const int s7 = prow & 7;
    const int pbase = prow * 16 + (lane & 1) * 8; // this lane's half-row base

    if (active) {
        // ---- pair-read: half-row (32 floats) into pinned registers ----
#define PR(j) nfloat4 v##j = W[pbase + (j ^ s7)];
        FOR8(PR)
#undef PR
#define PIN(j) asm volatile("" : "+v"(v##j.x), "+v"(v##j.y), "+v"(v##j.z), "+v"(v##j.w));
        FOR8(PIN)
#undef PIN

        // ---- row max (31 local + 1 pair-combine) -> tau0 = max - 1 ----
        nfloat4 m4 = v4max(v4max(v4max(v0, v1), v4max(v2, v3)),
                           v4max(v4max(v4, v5), v4max(v6, v7)));
        float m = fmaxf(fmaxf(m4.x, m4.y), fmaxf(m4.z, m4.w));
        m = fmaxf(m, __shfl_xor(m, 1, 64));

        float tau = m - 1.0f;
        int cprev = -1;                 // force at least one iteration
        float rfin = 1.0f;
        for (int it = 0; it < 40; ++it) {
            float s0 = 0.f, s1 = 0.f;
            int c0 = 0, c1 = 0;
#define ACC(j) {                                              \
            const float d0 = v##j.x - tau, d1 = v##j.y - tau; \
            const float d2 = v##j.z - tau, d3 = v##j.w - tau; \
            s0 += fmaxf(d0, 0.f); c0 += (d0 > 0.f);           \
            s1 += fmaxf(d1, 0.f); c1 += (d1 > 0.f);           \
            s0 += fmaxf(d2, 0.f); c0 += (d2 > 0.f);           \
            s1 += fmaxf(d3, 0.f); c1 += (d3 > 0.f); }
            FOR8(ACC)
#undef ACC
            float s = s0 + s1;
            int c = c0 + c1;
            // pair combine (DPP quad_perm; commutative -> identical in pair)
            s += __shfl_xor(s, 1, 64);
            c += __shfl_xor(c, 1, 64);
            const bool done = (c == cprev);   // nested supports: count fixed
            cprev = c;
            const float rr = __builtin_amdgcn_rcpf((float)c);
            rfin = rr;
            tau += (s - 1.0f) * rr;           // idempotent once converged
            if (__all(done)) break;
        }
        const float tau_out = tau - rfin;     // reference double -1: tau*-1/rho

        // ---- results back to the same LDS slots (same-lane same-addr) ----
#define OW(j) {                                       \
        nfloat4 t;                                    \
        t.x = fmaxf(0.f, v##j.x - tau_out);           \
        t.y = fmaxf(0.f, v##j.y - tau_out);           \
        t.z = fmaxf(0.f, v##j.z - tau_out);           \
        t.w = fmaxf(0.f, v##j.w - tau_out);           \
        W[pbase + (j ^ s7)] = t; }
        FOR8(OW)
#undef OW
    }
    __syncthreads();

    // ---- stage out: LDS swizzled -> global coalesced (nontemporal) ----
    if (active) {
        if (full) {
#pragma unroll
            for (int i = 0; i < 8; ++i) {
                const int r = i * 4 + hi4;
                __builtin_nontemporal_store(W[r * 16 + (l15 ^ (r & 7))],
                                            &ov[gbase + i * 64 + lane]);
            }
        } else {
#pragma unroll
            for (int i = 0; i < 8; ++i) {
                const int r = i * 4 + hi4;
                if (gbase + i * 64 + lane < f4max)
                    __builtin_nontemporal_store(W[r * 16 + (l15 ^ (r & 7))],
                                                &ov[gbase + i * 64 + lane]);
            }
        }
    }
}

extern "C" void kernel_launch(void* const* d_in, const int* in_sizes, int n_in,
                              void* d_out, int out_size, void* d_ws, size_t ws_size,
                              hipStream_t stream) {
    const float* x = (const float*)d_in[0];
    float* out = (float*)d_out;
    const long long n_rows = in_sizes[0] / 64;

    const int block = 256;                        // 4 waves = 128 rows / block
    const long long grid = (n_rows + 127) / 128;  // 8192 for 1M rows
    sparsemax_pairlds<<<(int)grid, block, 0, stream>>>(x, out, n_rows);
}

// Round 13
// 81.420 us; speedup vs baseline: 1.3759x; 1.0396x over previous
//
#include <hip/hip_runtime.h>
#include <hip/hip_bf16.h>
#include <math.h>

// Sparsemax over rows of [N_ROWS, 64] fp32 — pair-per-row registers, LDS as
// transpose buffer, NO BARRIERS (wave-private LDS slices), no result-write.
//
// Ladder: r8 regs-only 145us (scattered VMEM) -> r10 granule+DPP 102.7us
// (VALU-co-bound) -> r11 LDS-resident 112us (DS latency) -> r12 LDS-transpose
// + register Michelot 84.6us. r12 residuals: 2.1M LDS bank-conflict cycles,
// and __syncthreads lockstepping 4 waves/block through phases.
//
// This round: (1) drop both __syncthreads — each wave touches ONLY its own
// 8KB LDS slice, so wave-internal lgkmcnt ordering (compiler-inserted, asm
// memory fences keep phase order) is sufficient; waves pipeline phases
// independently. (2) stage-out reads the ORIGINAL values (still in LDS) and
// broadcasts the row's tau via one __shfl per store instead of writing
// results back through LDS (saves 8 ds_write_b128 per wave).
//
// Michelot fixed point (z=1 simplex threshold), all decisions fp32
// (r6: fp16 flipped the support boundary -> 1/rho output jumps):
//   tau0 = max(x)-1 ; tau += (sum(max(0,x-tau))-1)/c ; stop when c fixed
//   (supports nested/shrinking; update idempotent at the fixed point).
//   reference's double -1: tau_out = tau* - 1/rho ; out = max(0, x - tau_out)

typedef float nfloat4 __attribute__((ext_vector_type(4)));

#define FOR8(OP) OP(0) OP(1) OP(2) OP(3) OP(4) OP(5) OP(6) OP(7)

__device__ __forceinline__ nfloat4 v4max(nfloat4 a, nfloat4 b) {
    nfloat4 r;
    r.x = fmaxf(a.x, b.x); r.y = fmaxf(a.y, b.y);
    r.z = fmaxf(a.z, b.z); r.w = fmaxf(a.w, b.w);
    return r;
}

__global__ __launch_bounds__(256) void sparsemax_nosync(
    const float* __restrict__ x, float* __restrict__ out, long long n_rows) {
    __shared__ nfloat4 lds4[4][512];   // 8 KB per wave (wave-private slice)
    const int lane = threadIdx.x & 63;
    const int w = threadIdx.x >> 6;
    const long long gw = (long long)blockIdx.x * 4 + w;
    const long long row0 = gw * 32;               // 32 rows per wave
    if (row0 >= n_rows) return;                   // whole-wave uniform exit
    nfloat4* W = lds4[w];

    const nfloat4* __restrict__ xv = reinterpret_cast<const nfloat4*>(x);
    nfloat4* __restrict__ ov = reinterpret_cast<nfloat4*>(out);
    const long long gbase = row0 * 16;            // f4 index of tile
    const long long f4max = n_rows * 16;

    const bool full = (row0 + 32) <= n_rows;
    const int hi4 = lane >> 4;
    const int l15 = lane & 15;

    // ---- stage in: global coalesced -> LDS swizzled ----
    if (full) {
#pragma unroll
        for (int i = 0; i < 8; ++i) {
            const int r = i * 4 + hi4;
            W[r * 16 + (l15 ^ (r & 7))] = xv[gbase + i * 64 + lane];
        }
    } else {
#pragma unroll
        for (int i = 0; i < 8; ++i) {
            const int r = i * 4 + hi4;
            nfloat4 t = {0.f, 0.f, 0.f, 0.f};
            if (gbase + i * 64 + lane < f4max) t = xv[gbase + i * 64 + lane];
            W[r * 16 + (l15 ^ (r & 7))] = t;
        }
    }
    asm volatile("" ::: "memory");   // phase order: writes before pair-reads

    const int prow = lane >> 1;                   // tile-local row of this pair
    const int s7 = prow & 7;
    const int pbase = prow * 16 + (lane & 1) * 8; // this lane's half-row base

    // ---- pair-read: half-row (32 floats) into pinned registers ----
#define PR(j) nfloat4 v##j = W[pbase + (j ^ s7)];
    FOR8(PR)
#undef PR
#define PIN(j) asm volatile("" : "+v"(v##j.x), "+v"(v##j.y), "+v"(v##j.z), "+v"(v##j.w));
    FOR8(PIN)
#undef PIN

    // ---- row max (local 31 + 1 pair-combine) -> tau0 = max - 1 ----
    nfloat4 m4 = v4max(v4max(v4max(v0, v1), v4max(v2, v3)),
                       v4max(v4max(v4, v5), v4max(v6, v7)));
    float m = fmaxf(fmaxf(m4.x, m4.y), fmaxf(m4.z, m4.w));
    m = fmaxf(m, __shfl_xor(m, 1, 64));

    float tau = m - 1.0f;
    int cprev = -1;                 // force at least one iteration
    float rfin = 1.0f;
    for (int it = 0; it < 40; ++it) {
        float s0 = 0.f, s1 = 0.f;
        int c0 = 0, c1 = 0;
#define ACC(j) {                                              \
        const float d0 = v##j.x - tau, d1 = v##j.y - tau;     \
        const float d2 = v##j.z - tau, d3 = v##j.w - tau;     \
        s0 += fmaxf(d0, 0.f); c0 += (d0 > 0.f);               \
        s1 += fmaxf(d1, 0.f); c1 += (d1 > 0.f);               \
        s0 += fmaxf(d2, 0.f); c0 += (d2 > 0.f);               \
        s1 += fmaxf(d3, 0.f); c1 += (d3 > 0.f); }
        FOR8(ACC)
#undef ACC
        float s = s0 + s1;
        int c = c0 + c1;
        // pair combine (DPP quad_perm; commutative -> identical in pair)
        s += __shfl_xor(s, 1, 64);
        c += __shfl_xor(c, 1, 64);
        const bool done = (c == cprev);   // nested supports: count fixed
        cprev = c;
        const float rr = __builtin_amdgcn_rcpf((float)c);
        rfin = rr;
        tau += (s - 1.0f) * rr;           // idempotent once converged
        if (__all(done)) break;
    }
    const float tau_out = tau - rfin;     // reference double -1: tau* - 1/rho

    asm volatile("" ::: "memory");   // phase order: reads of originals below

    // ---- stage out: originals from LDS + tau via shfl -> coalesced NT store ----
    if (full) {
#pragma unroll
        for (int i = 0; i < 8; ++i) {
            const int r = i * 4 + hi4;
            const float tr = __shfl(tau_out, 8 * i + 2 * hi4, 64);
            const nfloat4 v = W[r * 16 + (l15 ^ (r & 7))];
            nfloat4 t;
            t.x = fmaxf(0.f, v.x - tr);
            t.y = fmaxf(0.f, v.y - tr);
            t.z = fmaxf(0.f, v.z - tr);
            t.w = fmaxf(0.f, v.w - tr);
            __builtin_nontemporal_store(t, &ov[gbase + i * 64 + lane]);
        }
    } else {
#pragma unroll
        for (int i = 0; i < 8; ++i) {
            const int r = i * 4 + hi4;
            const float tr = __shfl(tau_out, 8 * i + 2 * hi4, 64);
            const nfloat4 v = W[r * 16 + (l15 ^ (r & 7))];
            nfloat4 t;
            t.x = fmaxf(0.f, v.x - tr);
            t.y = fmaxf(0.f, v.y - tr);
            t.z = fmaxf(0.f, v.z - tr);
            t.w = fmaxf(0.f, v.w - tr);
            if (gbase + i * 64 + lane < f4max)
                __builtin_nontemporal_store(t, &ov[gbase + i * 64 + lane]);
        }
    }
}

extern "C" void kernel_launch(void* const* d_in, const int* in_sizes, int n_in,
                              void* d_out, int out_size, void* d_ws, size_t ws_size,
                              hipStream_t stream) {
    const float* x = (const float*)d_in[0];
    float* out = (float*)d_out;
    const long long n_rows = in_sizes[0] / 64;

    const int block = 256;                        // 4 independent waves / block
    const long long grid = (n_rows + 127) / 128;  // 8192 for 1M rows
    sparsemax_nosync<<<(int)grid, block, 0, stream>>>(x, out, n_rows);
}